// Round 1
// baseline (6664.330 us; speedup 1.0000x reference)
//
#include <hip/hip_runtime.h>

// ---------------------------------------------------------------------------
// GCN: 3x (GEMM -> SpMM scatter-add -> [BN -> ReLU])
// N=50000 nodes, 128 feats, E=1.6M edges, final F_out=40.
// b0/b1 dropped: per-feature constant shifts cancel in BN mean-subtraction.
// ---------------------------------------------------------------------------

constexpr int   N_NODES = 50000;
constexpr int   E_EDGES = 1600000;
constexpr float BN_EPS  = 1e-5f;

// ---------------- GEMM: H[N][FOUT] = X[N][128] @ W[128][FOUT] --------------
// W in LDS (128*FOUT), x-tile in LDS padded (+1) to kill bank conflicts.
// Each active thread computes a 4x4 register tile (4 rows x 4 features).
template <int FOUT, int ROWS>
__global__ __launch_bounds__(256) void gemm_ker(const float* __restrict__ X,
                                                const float* __restrict__ W,
                                                float* __restrict__ H) {
  constexpr int FQ    = FOUT / 4;        // feature quads
  constexpr int RQ    = ROWS / 4;        // row quads
  constexpr int UNITS = FQ * RQ;
  static_assert(UNITS <= 256, "tile too big");

  __shared__ float Ws[128 * FOUT];
  __shared__ float Xs[ROWS][129];        // +1 pad

  const int tid  = threadIdx.x;
  const int row0 = blockIdx.x * ROWS;

  // cooperative load W (row-major [k][f])
  for (int i = tid; i < 128 * FOUT; i += 256) Ws[i] = W[i];

  // cooperative load x tile (float4 along k), guard tail rows by clamping
  for (int q = tid; q < ROWS * 32; q += 256) {
    const int r  = q >> 5;
    const int k4 = (q & 31) * 4;
    int gr = row0 + r;
    if (gr >= N_NODES) gr = N_NODES - 1;
    const float4 v = *(const float4*)(X + (long)gr * 128 + k4);
    Xs[r][k4 + 0] = v.x; Xs[r][k4 + 1] = v.y;
    Xs[r][k4 + 2] = v.z; Xs[r][k4 + 3] = v.w;
  }
  __syncthreads();

  if (tid < UNITS) {
    const int fq = (tid % FQ) * 4;
    const int rg = (tid / FQ) * 4;
    float4 a0 = {0, 0, 0, 0}, a1 = a0, a2 = a0, a3 = a0;
#pragma unroll 8
    for (int k = 0; k < 128; ++k) {
      const float4 wv = *(const float4*)(Ws + k * FOUT + fq);
      const float x0 = Xs[rg + 0][k];
      const float x1 = Xs[rg + 1][k];
      const float x2 = Xs[rg + 2][k];
      const float x3 = Xs[rg + 3][k];
      a0.x += x0 * wv.x; a0.y += x0 * wv.y; a0.z += x0 * wv.z; a0.w += x0 * wv.w;
      a1.x += x1 * wv.x; a1.y += x1 * wv.y; a1.z += x1 * wv.z; a1.w += x1 * wv.w;
      a2.x += x2 * wv.x; a2.y += x2 * wv.y; a2.z += x2 * wv.z; a2.w += x2 * wv.w;
      a3.x += x3 * wv.x; a3.y += x3 * wv.y; a3.z += x3 * wv.z; a3.w += x3 * wv.w;
    }
    const float4 accs[4] = {a0, a1, a2, a3};
#pragma unroll
    for (int i = 0; i < 4; ++i) {
      const int gr = row0 + rg + i;
      if (gr < N_NODES) *(float4*)(H + (long)gr * FOUT + fq) = accs[i];
    }
  }
}

// ---------------- SpMM: A[row] += w * H[col], atomic scatter ----------------
// one thread per (edge, float4 chunk); 32 consecutive threads gather one
// contiguous 512B row of H (F=128), then 4 atomicAdds to the destination row.
template <int F>
__global__ __launch_bounds__(256) void spmm_ker(const int* __restrict__ rows,
                                                const int* __restrict__ cols,
                                                const float* __restrict__ ew,
                                                const float* __restrict__ H,
                                                float* __restrict__ A) {
  constexpr int Q = F / 4;
  const long gid = (long)blockIdx.x * 256 + threadIdx.x;
  const int  e   = (int)(gid / Q);
  const int  q   = (int)(gid % Q);
  if (e >= E_EDGES) return;
  const int   c  = cols[e];
  const int   r  = rows[e];
  const float wt = ew[e];
  const float4 v = *(const float4*)(H + (long)c * F + q * 4);
  float* dst = A + (long)r * F + q * 4;
  atomicAdd(dst + 0, v.x * wt);
  atomicAdd(dst + 1, v.y * wt);
  atomicAdd(dst + 2, v.z * wt);
  atomicAdd(dst + 3, v.w * wt);
}

// ---------------- BN stats: per-column sum & sumsq -------------------------
constexpr int BN_BLOCKS   = 512;
constexpr int BN_ROWS_PER = (N_NODES + BN_BLOCKS - 1) / BN_BLOCKS;  // 98

__global__ __launch_bounds__(256) void bn_stats_ker(const float* __restrict__ A,
                                                    float* __restrict__ stats) {
  const int tid = threadIdx.x;
  const int c   = tid & 127;
  const int rs  = tid >> 7;  // 0/1
  const int r0  = blockIdx.x * BN_ROWS_PER;
  const int re  = min(r0 + BN_ROWS_PER, N_NODES);
  float s = 0.f, sq = 0.f;
  for (int r = r0 + rs; r < re; r += 2) {
    const float v = A[(long)r * 128 + c];
    s += v; sq += v * v;
  }
  atomicAdd(&stats[c], s);
  atomicAdd(&stats[128 + c], sq);
}

__global__ void bn_final_ker(const float* __restrict__ stats,
                             const float* __restrict__ g,
                             const float* __restrict__ be,
                             float* __restrict__ ss) {
  const int c = threadIdx.x;  // 128 threads
  const float mean = stats[c] * (1.0f / N_NODES);
  const float var  = stats[128 + c] * (1.0f / N_NODES) - mean * mean;
  const float sc   = g[c] * rsqrtf(var + BN_EPS);
  ss[c]       = sc;
  ss[128 + c] = be[c] - mean * sc;
}

// ---------------- normalize + ReLU, in place -------------------------------
__global__ __launch_bounds__(256) void norm_relu_ker(float* __restrict__ A,
                                                     const float* __restrict__ ss) {
  const long gid = (long)blockIdx.x * 256 + threadIdx.x;  // quad index
  if (gid >= (long)N_NODES * 32) return;
  const int c4 = (int)(gid & 31) * 4;
  float4 v = *(float4*)(A + gid * 4);
  const float4 sc = *(const float4*)(ss + c4);
  const float4 sh = *(const float4*)(ss + 128 + c4);
  v.x = fmaxf(v.x * sc.x + sh.x, 0.f);
  v.y = fmaxf(v.y * sc.y + sh.y, 0.f);
  v.z = fmaxf(v.z * sc.z + sh.z, 0.f);
  v.w = fmaxf(v.w * sc.w + sh.w, 0.f);
  *(float4*)(A + gid * 4) = v;
}

// ---------------- out init with bias b2 ------------------------------------
__global__ __launch_bounds__(256) void bias_init_ker(float* __restrict__ out,
                                                     const float* __restrict__ b) {
  const long gid = (long)blockIdx.x * 256 + threadIdx.x;
  if (gid >= (long)N_NODES * 40) return;
  out[gid] = b[(int)(gid % 40)];
}

// ---------------------------------------------------------------------------
extern "C" void kernel_launch(void* const* d_in, const int* in_sizes, int n_in,
                              void* d_out, int out_size, void* d_ws, size_t ws_size,
                              hipStream_t stream) {
  const float* x    = (const float*)d_in[0];
  const int*   erow = (const int*)d_in[1];
  const int*   ecol = (const int*)d_in[2];
  const float* ew   = (const float*)d_in[3];
  const float* W0   = (const float*)d_in[4];
  const float* g0   = (const float*)d_in[6];
  const float* be0  = (const float*)d_in[7];
  const float* W1   = (const float*)d_in[8];
  const float* g1   = (const float*)d_in[10];
  const float* be1  = (const float*)d_in[11];
  const float* W2   = (const float*)d_in[12];
  const float* b2   = (const float*)d_in[13];
  float* out = (float*)d_out;

  float* h     = (float*)d_ws;            // N*128
  float* agg   = h + (long)N_NODES * 128; // N*128
  float* stats = agg + (long)N_NODES * 128;
  float* ss    = stats + 256;

  const int g_gemm128 = (N_NODES + 31) / 32;    // 1563
  const int g_gemm40  = (N_NODES + 95) / 96;    // 521
  const int g_spmm128 = (E_EDGES * 32 + 255) / 256;
  const int g_spmm40  = (E_EDGES * 10 + 255) / 256;
  const int g_norm    = (N_NODES * 32 + 255) / 256;
  const int g_bias    = (N_NODES * 40 + 255) / 256;

  // ---- layer 0 ----
  gemm_ker<128, 32><<<g_gemm128, 256, 0, stream>>>(x, W0, h);
  hipMemsetAsync(agg, 0, (size_t)N_NODES * 128 * 4, stream);
  spmm_ker<128><<<g_spmm128, 256, 0, stream>>>(erow, ecol, ew, h, agg);
  hipMemsetAsync(stats, 0, 256 * 4, stream);
  bn_stats_ker<<<BN_BLOCKS, 256, 0, stream>>>(agg, stats);
  bn_final_ker<<<1, 128, 0, stream>>>(stats, g0, be0, ss);
  norm_relu_ker<<<g_norm, 256, 0, stream>>>(agg, ss);   // x1 now in agg

  // ---- layer 1 ----
  gemm_ker<128, 32><<<g_gemm128, 256, 0, stream>>>(agg, W1, h);
  hipMemsetAsync(agg, 0, (size_t)N_NODES * 128 * 4, stream);
  spmm_ker<128><<<g_spmm128, 256, 0, stream>>>(erow, ecol, ew, h, agg);
  hipMemsetAsync(stats, 0, 256 * 4, stream);
  bn_stats_ker<<<BN_BLOCKS, 256, 0, stream>>>(agg, stats);
  bn_final_ker<<<1, 128, 0, stream>>>(stats, g1, be1, ss);
  norm_relu_ker<<<g_norm, 256, 0, stream>>>(agg, ss);   // x2 now in agg

  // ---- layer 2 (128 -> 40, bias b2, no BN) ----
  gemm_ker<40, 96><<<g_gemm40, 256, 0, stream>>>(agg, W2, h);  // h as [N][40]
  bias_init_ker<<<g_bias, 256, 0, stream>>>(out, b2);
  spmm_ker<40><<<g_spmm40, 256, 0, stream>>>(erow, ecol, ew, h, out);
}

// Round 2
// 813.732 us; speedup vs baseline: 8.1898x; 8.1898x over previous
//
#include <hip/hip_runtime.h>

// ---------------------------------------------------------------------------
// GCN: per-call CSR build (hist/scan/scatter), then 3x (GEMM -> CSR-SpMM).
// BN affine+ReLU fused into the next layer's GEMM input load.
// b0/b1 dropped: constant per-feature shifts cancel in BN mean-subtraction.
// ---------------------------------------------------------------------------

constexpr int   N_NODES = 50000;
constexpr int   E_EDGES = 1600000;
constexpr float BN_EPS  = 1e-5f;

// ========================= CSR build =========================
__global__ __launch_bounds__(256) void hist_ker(const int* __restrict__ rows,
                                                int* __restrict__ deg) {
  const int gid = blockIdx.x * 256 + threadIdx.x;
  if (gid < E_EDGES) atomicAdd(&deg[rows[gid]], 1);
}

// single-block scan: 1024 threads, each owns a 49-row chunk.
__global__ __launch_bounds__(1024) void scan_ker(int* __restrict__ deg,
                                                 int* __restrict__ rowptr) {
  constexpr int C = (N_NODES + 1023) / 1024;  // 49
  const int t  = threadIdx.x;
  const int lo = t * C;
  const int hi = min(lo + C, N_NODES);
  int s = 0;
  for (int i = lo; i < hi; ++i) s += deg[i];
  __shared__ int sh[1024];
  sh[t] = s;
  __syncthreads();
  for (int off = 1; off < 1024; off <<= 1) {
    int v = (t >= off) ? sh[t - off] : 0;
    __syncthreads();
    if (t >= off) sh[t] += v;
    __syncthreads();
  }
  int run = (t == 0) ? 0 : sh[t - 1];
  for (int i = lo; i < hi; ++i) {
    const int d = deg[i];
    rowptr[i] = run;
    run += d;
    deg[i] = 0;  // becomes the scatter cursor
  }
  if (hi == N_NODES) rowptr[N_NODES] = run;  // all qualifying threads write total
}

__global__ __launch_bounds__(256) void scatter_ker(const int* __restrict__ rows,
                                                   const int* __restrict__ cols,
                                                   const float* __restrict__ ew,
                                                   const int* __restrict__ rowptr,
                                                   int* __restrict__ cursor,
                                                   int2* __restrict__ se) {
  const int gid = blockIdx.x * 256 + threadIdx.x;
  if (gid >= E_EDGES) return;
  const int r   = rows[gid];
  const int pos = rowptr[r] + atomicAdd(&cursor[r], 1);
  int2 v;
  v.x = cols[gid];
  v.y = __float_as_int(ew[gid]);
  se[pos] = v;
}

// ========================= GEMM =========================
// H[N][FOUT] = act(X)[N][128] @ W[128][FOUT];  act = BN-affine+ReLU if FUSE.
template <int FOUT, int ROWS, bool FUSE>
__global__ __launch_bounds__(256) void gemm_ker(const float* __restrict__ X,
                                                const float* __restrict__ W,
                                                float* __restrict__ H,
                                                const float* __restrict__ ss) {
  constexpr int FQ    = FOUT / 4;
  constexpr int RQ    = ROWS / 4;
  constexpr int UNITS = FQ * RQ;
  static_assert(UNITS <= 256, "tile too big");

  __shared__ float Ws[128 * FOUT];
  __shared__ float Xs[ROWS][129];

  const int tid  = threadIdx.x;
  const int row0 = blockIdx.x * ROWS;

  for (int i = tid; i < 128 * FOUT; i += 256) Ws[i] = W[i];

  for (int q = tid; q < ROWS * 32; q += 256) {
    const int r  = q >> 5;
    const int k4 = (q & 31) * 4;
    int gr = row0 + r;
    if (gr >= N_NODES) gr = N_NODES - 1;
    float4 v = *(const float4*)(X + (long)gr * 128 + k4);
    if constexpr (FUSE) {
      const float4 sc = *(const float4*)(ss + k4);
      const float4 sh = *(const float4*)(ss + 128 + k4);
      v.x = fmaxf(v.x * sc.x + sh.x, 0.f);
      v.y = fmaxf(v.y * sc.y + sh.y, 0.f);
      v.z = fmaxf(v.z * sc.z + sh.z, 0.f);
      v.w = fmaxf(v.w * sc.w + sh.w, 0.f);
    }
    Xs[r][k4 + 0] = v.x; Xs[r][k4 + 1] = v.y;
    Xs[r][k4 + 2] = v.z; Xs[r][k4 + 3] = v.w;
  }
  __syncthreads();

  if (tid < UNITS) {
    const int fq = (tid % FQ) * 4;
    const int rg = (tid / FQ) * 4;
    float4 a0 = {0, 0, 0, 0}, a1 = a0, a2 = a0, a3 = a0;
#pragma unroll 8
    for (int k = 0; k < 128; ++k) {
      const float4 wv = *(const float4*)(Ws + k * FOUT + fq);
      const float x0 = Xs[rg + 0][k];
      const float x1 = Xs[rg + 1][k];
      const float x2 = Xs[rg + 2][k];
      const float x3 = Xs[rg + 3][k];
      a0.x += x0 * wv.x; a0.y += x0 * wv.y; a0.z += x0 * wv.z; a0.w += x0 * wv.w;
      a1.x += x1 * wv.x; a1.y += x1 * wv.y; a1.z += x1 * wv.z; a1.w += x1 * wv.w;
      a2.x += x2 * wv.x; a2.y += x2 * wv.y; a2.z += x2 * wv.z; a2.w += x2 * wv.w;
      a3.x += x3 * wv.x; a3.y += x3 * wv.y; a3.z += x3 * wv.z; a3.w += x3 * wv.w;
    }
    const float4 accs[4] = {a0, a1, a2, a3};
#pragma unroll
    for (int i = 0; i < 4; ++i) {
      const int gr = row0 + rg + i;
      if (gr < N_NODES) *(float4*)(H + (long)gr * FOUT + fq) = accs[i];
    }
  }
}

// ========================= CSR SpMM =========================
// F=128: one wave per row; lane owns 2 contiguous feats (float2 gather).
__global__ __launch_bounds__(256) void spmm_csr128_ker(const int* __restrict__ rowptr,
                                                       const int2* __restrict__ se,
                                                       const float* __restrict__ H,
                                                       float* __restrict__ A) {
  const int gid  = blockIdx.x * 256 + threadIdx.x;
  const int lane = threadIdx.x & 63;
  const int wid  = __builtin_amdgcn_readfirstlane(gid >> 6);
  if (wid >= N_NODES) return;
  const int beg = rowptr[wid];
  const int end = rowptr[wid + 1];
  const float* __restrict__ Hl = H + lane * 2;
  float acc0 = 0.f, acc1 = 0.f;
  int e = beg;
  for (; e + 4 <= end; e += 4) {
    const int2 e0 = se[e + 0], e1 = se[e + 1], e2 = se[e + 2], e3 = se[e + 3];
    const float2 v0 = *(const float2*)(Hl + (long)e0.x * 128);
    const float2 v1 = *(const float2*)(Hl + (long)e1.x * 128);
    const float2 v2 = *(const float2*)(Hl + (long)e2.x * 128);
    const float2 v3 = *(const float2*)(Hl + (long)e3.x * 128);
    const float w0 = __int_as_float(e0.y), w1 = __int_as_float(e1.y);
    const float w2 = __int_as_float(e2.y), w3 = __int_as_float(e3.y);
    acc0 += w0 * v0.x; acc1 += w0 * v0.y;
    acc0 += w1 * v1.x; acc1 += w1 * v1.y;
    acc0 += w2 * v2.x; acc1 += w2 * v2.y;
    acc0 += w3 * v3.x; acc1 += w3 * v3.y;
  }
  for (; e < end; ++e) {
    const int2  ed = se[e];
    const float2 v = *(const float2*)(Hl + (long)ed.x * 128);
    const float  w = __int_as_float(ed.y);
    acc0 += w * v.x; acc1 += w * v.y;
  }
  float2 o; o.x = acc0; o.y = acc1;
  *(float2*)(A + (long)wid * 128 + lane * 2) = o;
}

// F=40 + bias: one wave per row, lanes 0..39 active.
__global__ __launch_bounds__(256) void spmm_csr40_ker(const int* __restrict__ rowptr,
                                                      const int2* __restrict__ se,
                                                      const float* __restrict__ H,
                                                      const float* __restrict__ b,
                                                      float* __restrict__ out) {
  const int gid  = blockIdx.x * 256 + threadIdx.x;
  const int lane = threadIdx.x & 63;
  const int wid  = __builtin_amdgcn_readfirstlane(gid >> 6);
  if (wid >= N_NODES) return;
  const int beg = rowptr[wid];
  const int end = rowptr[wid + 1];
  const bool act = lane < 40;
  const int  l   = act ? lane : 0;
  float acc = 0.f;
  int e = beg;
  for (; e + 4 <= end; e += 4) {
    const int2 e0 = se[e + 0], e1 = se[e + 1], e2 = se[e + 2], e3 = se[e + 3];
    const float v0 = H[(long)e0.x * 40 + l];
    const float v1 = H[(long)e1.x * 40 + l];
    const float v2 = H[(long)e2.x * 40 + l];
    const float v3 = H[(long)e3.x * 40 + l];
    acc += __int_as_float(e0.y) * v0;
    acc += __int_as_float(e1.y) * v1;
    acc += __int_as_float(e2.y) * v2;
    acc += __int_as_float(e3.y) * v3;
  }
  for (; e < end; ++e) {
    const int2 ed = se[e];
    acc += __int_as_float(ed.y) * H[(long)ed.x * 40 + l];
  }
  if (act) out[(long)wid * 40 + lane] = acc + b[lane];
}

// ========================= BatchNorm =========================
constexpr int BN_BLOCKS   = 512;
constexpr int BN_ROWS_PER = (N_NODES + BN_BLOCKS - 1) / BN_BLOCKS;  // 98

__global__ __launch_bounds__(256) void bn_stats_ker(const float* __restrict__ A,
                                                    float* __restrict__ stats) {
  const int tid = threadIdx.x;
  const int c   = tid & 127;
  const int rs  = tid >> 7;
  const int r0  = blockIdx.x * BN_ROWS_PER;
  const int re  = min(r0 + BN_ROWS_PER, N_NODES);
  float s = 0.f, sq = 0.f;
  for (int r = r0 + rs; r < re; r += 2) {
    const float v = A[(long)r * 128 + c];
    s += v; sq += v * v;
  }
  atomicAdd(&stats[c], s);
  atomicAdd(&stats[128 + c], sq);
}

__global__ void bn_final_ker(const float* __restrict__ stats,
                             const float* __restrict__ g,
                             const float* __restrict__ be,
                             float* __restrict__ ss) {
  const int c = threadIdx.x;  // 128 threads
  const float mean = stats[c] * (1.0f / N_NODES);
  const float var  = stats[128 + c] * (1.0f / N_NODES) - mean * mean;
  const float sc   = g[c] * rsqrtf(var + BN_EPS);
  ss[c]       = sc;
  ss[128 + c] = be[c] - mean * sc;
}

// ---------------------------------------------------------------------------
extern "C" void kernel_launch(void* const* d_in, const int* in_sizes, int n_in,
                              void* d_out, int out_size, void* d_ws, size_t ws_size,
                              hipStream_t stream) {
  const float* x    = (const float*)d_in[0];
  const int*   erow = (const int*)d_in[1];
  const int*   ecol = (const int*)d_in[2];
  const float* ew   = (const float*)d_in[3];
  const float* W0   = (const float*)d_in[4];
  const float* g0   = (const float*)d_in[6];
  const float* be0  = (const float*)d_in[7];
  const float* W1   = (const float*)d_in[8];
  const float* g1   = (const float*)d_in[10];
  const float* be1  = (const float*)d_in[11];
  const float* W2   = (const float*)d_in[12];
  const float* b2   = (const float*)d_in[13];
  float* out = (float*)d_out;

  // workspace layout (floats/ints); se kept 8B-aligned (even int offset)
  float* h      = (float*)d_ws;                 // N*128
  float* agg    = h + (long)N_NODES * 128;      // N*128
  float* stats  = agg + (long)N_NODES * 128;    // 256
  float* ss     = stats + 256;                  // 256
  int*   rowptr = (int*)(ss + 256);             // N+1 (pad to 50002)
  int*   cursor = rowptr + 50002;               // N
  int2*  se     = (int2*)(cursor + 50000);      // E

  const int g_e      = (E_EDGES + 255) / 256;        // 6250
  const int g_gemm128 = (N_NODES + 31) / 32;         // 1563
  const int g_gemm40  = (N_NODES + 95) / 96;         // 521
  const int g_spmm    = (N_NODES * 64) / 256;        // 12500 (exact)

  // ---- CSR build (edges are static; rebuilt each call, no state carried) ----
  hipMemsetAsync(cursor, 0, (size_t)N_NODES * 4, stream);
  hist_ker<<<g_e, 256, 0, stream>>>(erow, cursor);
  scan_ker<<<1, 1024, 0, stream>>>(cursor, rowptr);
  scatter_ker<<<g_e, 256, 0, stream>>>(erow, ecol, ew, rowptr, cursor, se);

  // ---- layer 0 ----
  gemm_ker<128, 32, false><<<g_gemm128, 256, 0, stream>>>(x, W0, h, nullptr);
  spmm_csr128_ker<<<g_spmm, 256, 0, stream>>>(rowptr, se, h, agg);
  hipMemsetAsync(stats, 0, 256 * 4, stream);
  bn_stats_ker<<<BN_BLOCKS, 256, 0, stream>>>(agg, stats);
  bn_final_ker<<<1, 128, 0, stream>>>(stats, g0, be0, ss);

  // ---- layer 1 (BN0+ReLU fused into GEMM input load) ----
  gemm_ker<128, 32, true><<<g_gemm128, 256, 0, stream>>>(agg, W1, h, ss);
  spmm_csr128_ker<<<g_spmm, 256, 0, stream>>>(rowptr, se, h, agg);
  hipMemsetAsync(stats, 0, 256 * 4, stream);
  bn_stats_ker<<<BN_BLOCKS, 256, 0, stream>>>(agg, stats);
  bn_final_ker<<<1, 128, 0, stream>>>(stats, g1, be1, ss);

  // ---- layer 2 (BN1+ReLU fused into GEMM, bias b2 fused into SpMM) ----
  gemm_ker<40, 96, true><<<g_gemm40, 256, 0, stream>>>(agg, W2, h, ss);
  spmm_csr40_ker<<<g_spmm, 256, 0, stream>>>(rowptr, se, h, b2, out);
}

// Round 3
// 717.238 us; speedup vs baseline: 9.2917x; 1.1345x over previous
//
#include <hip/hip_runtime.h>

// ---------------------------------------------------------------------------
// GCN: per-call CSR build (hist / 3-phase parallel scan / scatter),
// then 3x (GEMM -> CSR-SpMM). BN affine+ReLU fused into next GEMM's load.
// b0/b1 dropped: constant per-feature shifts cancel in BN mean-subtraction.
// ---------------------------------------------------------------------------

constexpr int   N_NODES  = 50000;
constexpr int   E_EDGES  = 1600000;
constexpr float BN_EPS   = 1e-5f;
constexpr int   SCAN_BLK = (N_NODES + 255) / 256;  // 196

// ========================= CSR build =========================
__global__ __launch_bounds__(256) void hist_ker(const int* __restrict__ rows,
                                                int* __restrict__ deg) {
  const int gid = blockIdx.x * 256 + threadIdx.x;
  if (gid < E_EDGES) atomicAdd(&deg[rows[gid]], 1);
}

// phase 1: per-block sum of 256 degrees
__global__ __launch_bounds__(256) void scan1_ker(const int* __restrict__ deg,
                                                 int* __restrict__ partial) {
  const int r = blockIdx.x * 256 + threadIdx.x;
  int v = (r < N_NODES) ? deg[r] : 0;
#pragma unroll
  for (int o = 32; o > 0; o >>= 1) v += __shfl_down(v, o, 64);
  __shared__ int sh[4];
  if ((threadIdx.x & 63) == 0) sh[threadIdx.x >> 6] = v;
  __syncthreads();
  if (threadIdx.x == 0) partial[blockIdx.x] = sh[0] + sh[1] + sh[2] + sh[3];
}

// phase 2: single block scans SCAN_BLK partials -> exclusive block offsets
__global__ __launch_bounds__(256) void scan2_ker(const int* __restrict__ partial,
                                                 int* __restrict__ blockoff) {
  const int t = threadIdx.x;
  int v = (t < SCAN_BLK) ? partial[t] : 0;
  __shared__ int sh[256];
  sh[t] = v;
  __syncthreads();
  for (int off = 1; off < 256; off <<= 1) {
    int u = (t >= off) ? sh[t - off] : 0;
    __syncthreads();
    sh[t] += u;
    __syncthreads();
  }
  blockoff[t] = (t == 0) ? 0 : sh[t - 1];
}

// phase 3: intra-block scan -> rowptr; zero deg (becomes scatter cursor)
__global__ __launch_bounds__(256) void scan3_ker(int* __restrict__ deg,
                                                 const int* __restrict__ blockoff,
                                                 int* __restrict__ rowptr) {
  const int t = threadIdx.x;
  const int r = blockIdx.x * 256 + t;
  const int v = (r < N_NODES) ? deg[r] : 0;
  __shared__ int sh[256];
  sh[t] = v;
  __syncthreads();
  for (int off = 1; off < 256; off <<= 1) {
    int u = (t >= off) ? sh[t - off] : 0;
    __syncthreads();
    sh[t] += u;
    __syncthreads();
  }
  const int base = blockoff[blockIdx.x];
  if (r < N_NODES) {
    rowptr[r] = base + sh[t] - v;
    deg[r] = 0;
  }
  if (r == N_NODES - 1) rowptr[N_NODES] = base + sh[t];
}

__global__ __launch_bounds__(256) void scatter_ker(const int* __restrict__ rows,
                                                   const int* __restrict__ cols,
                                                   const float* __restrict__ ew,
                                                   const int* __restrict__ rowptr,
                                                   int* __restrict__ cursor,
                                                   int2* __restrict__ se) {
  const int gid = blockIdx.x * 256 + threadIdx.x;
  if (gid >= E_EDGES) return;
  const int r   = rows[gid];
  const int pos = rowptr[r] + atomicAdd(&cursor[r], 1);
  int2 v;
  v.x = cols[gid];
  v.y = __float_as_int(ew[gid]);
  se[pos] = v;
}

// ========================= GEMM =========================
// H[N][FOUT] = act(X)[N][128] @ W[128][FOUT];  act = BN-affine+ReLU if FUSE.
template <int FOUT, int ROWS, bool FUSE>
__global__ __launch_bounds__(256) void gemm_ker(const float* __restrict__ X,
                                                const float* __restrict__ W,
                                                float* __restrict__ H,
                                                const float* __restrict__ ss) {
  constexpr int FQ    = FOUT / 4;
  constexpr int RQ    = ROWS / 4;
  constexpr int UNITS = FQ * RQ;
  static_assert(UNITS <= 256, "tile too big");

  __shared__ float Ws[128 * FOUT];
  __shared__ float Xs[ROWS][129];

  const int tid  = threadIdx.x;
  const int row0 = blockIdx.x * ROWS;

  for (int i = tid; i < 128 * FOUT; i += 256) Ws[i] = W[i];

  for (int q = tid; q < ROWS * 32; q += 256) {
    const int r  = q >> 5;
    const int k4 = (q & 31) * 4;
    int gr = row0 + r;
    if (gr >= N_NODES) gr = N_NODES - 1;
    float4 v = *(const float4*)(X + (long)gr * 128 + k4);
    if constexpr (FUSE) {
      const float4 sc = *(const float4*)(ss + k4);
      const float4 sh = *(const float4*)(ss + 128 + k4);
      v.x = fmaxf(v.x * sc.x + sh.x, 0.f);
      v.y = fmaxf(v.y * sc.y + sh.y, 0.f);
      v.z = fmaxf(v.z * sc.z + sh.z, 0.f);
      v.w = fmaxf(v.w * sc.w + sh.w, 0.f);
    }
    Xs[r][k4 + 0] = v.x; Xs[r][k4 + 1] = v.y;
    Xs[r][k4 + 2] = v.z; Xs[r][k4 + 3] = v.w;
  }
  __syncthreads();

  if (tid < UNITS) {
    const int fq = (tid % FQ) * 4;
    const int rg = (tid / FQ) * 4;
    float4 a0 = {0, 0, 0, 0}, a1 = a0, a2 = a0, a3 = a0;
#pragma unroll 8
    for (int k = 0; k < 128; ++k) {
      const float4 wv = *(const float4*)(Ws + k * FOUT + fq);
      const float x0 = Xs[rg + 0][k];
      const float x1 = Xs[rg + 1][k];
      const float x2 = Xs[rg + 2][k];
      const float x3 = Xs[rg + 3][k];
      a0.x += x0 * wv.x; a0.y += x0 * wv.y; a0.z += x0 * wv.z; a0.w += x0 * wv.w;
      a1.x += x1 * wv.x; a1.y += x1 * wv.y; a1.z += x1 * wv.z; a1.w += x1 * wv.w;
      a2.x += x2 * wv.x; a2.y += x2 * wv.y; a2.z += x2 * wv.z; a2.w += x2 * wv.w;
      a3.x += x3 * wv.x; a3.y += x3 * wv.y; a3.z += x3 * wv.z; a3.w += x3 * wv.w;
    }
    const float4 accs[4] = {a0, a1, a2, a3};
#pragma unroll
    for (int i = 0; i < 4; ++i) {
      const int gr = row0 + rg + i;
      if (gr < N_NODES) *(float4*)(H + (long)gr * FOUT + fq) = accs[i];
    }
  }
}

// ========================= CSR SpMM =========================
// F=128: one wave per row; lane owns 2 contiguous feats (float2 gather).
__global__ __launch_bounds__(256) void spmm_csr128_ker(const int* __restrict__ rowptr,
                                                       const int2* __restrict__ se,
                                                       const float* __restrict__ H,
                                                       float* __restrict__ A) {
  const int gid  = blockIdx.x * 256 + threadIdx.x;
  const int lane = threadIdx.x & 63;
  const int wid  = __builtin_amdgcn_readfirstlane(gid >> 6);
  if (wid >= N_NODES) return;
  const int beg = rowptr[wid];
  const int end = rowptr[wid + 1];
  const float* __restrict__ Hl = H + lane * 2;
  float acc0 = 0.f, acc1 = 0.f;
  int e = beg;
  for (; e + 4 <= end; e += 4) {
    const int2 e0 = se[e + 0], e1 = se[e + 1], e2 = se[e + 2], e3 = se[e + 3];
    const float2 v0 = *(const float2*)(Hl + (long)e0.x * 128);
    const float2 v1 = *(const float2*)(Hl + (long)e1.x * 128);
    const float2 v2 = *(const float2*)(Hl + (long)e2.x * 128);
    const float2 v3 = *(const float2*)(Hl + (long)e3.x * 128);
    const float w0 = __int_as_float(e0.y), w1 = __int_as_float(e1.y);
    const float w2 = __int_as_float(e2.y), w3 = __int_as_float(e3.y);
    acc0 += w0 * v0.x; acc1 += w0 * v0.y;
    acc0 += w1 * v1.x; acc1 += w1 * v1.y;
    acc0 += w2 * v2.x; acc1 += w2 * v2.y;
    acc0 += w3 * v3.x; acc1 += w3 * v3.y;
  }
  for (; e < end; ++e) {
    const int2  ed = se[e];
    const float2 v = *(const float2*)(Hl + (long)ed.x * 128);
    const float  w = __int_as_float(ed.y);
    acc0 += w * v.x; acc1 += w * v.y;
  }
  float2 o; o.x = acc0; o.y = acc1;
  *(float2*)(A + (long)wid * 128 + lane * 2) = o;
}

// F=40 + bias: one wave per row, lanes 0..39 active.
__global__ __launch_bounds__(256) void spmm_csr40_ker(const int* __restrict__ rowptr,
                                                      const int2* __restrict__ se,
                                                      const float* __restrict__ H,
                                                      const float* __restrict__ b,
                                                      float* __restrict__ out) {
  const int gid  = blockIdx.x * 256 + threadIdx.x;
  const int lane = threadIdx.x & 63;
  const int wid  = __builtin_amdgcn_readfirstlane(gid >> 6);
  if (wid >= N_NODES) return;
  const int beg = rowptr[wid];
  const int end = rowptr[wid + 1];
  const bool act = lane < 40;
  const int  l   = act ? lane : 0;
  float acc = 0.f;
  int e = beg;
  for (; e + 4 <= end; e += 4) {
    const int2 e0 = se[e + 0], e1 = se[e + 1], e2 = se[e + 2], e3 = se[e + 3];
    const float v0 = H[(long)e0.x * 40 + l];
    const float v1 = H[(long)e1.x * 40 + l];
    const float v2 = H[(long)e2.x * 40 + l];
    const float v3 = H[(long)e3.x * 40 + l];
    acc += __int_as_float(e0.y) * v0;
    acc += __int_as_float(e1.y) * v1;
    acc += __int_as_float(e2.y) * v2;
    acc += __int_as_float(e3.y) * v3;
  }
  for (; e < end; ++e) {
    const int2 ed = se[e];
    acc += __int_as_float(ed.y) * H[(long)ed.x * 40 + l];
  }
  if (act) out[(long)wid * 40 + lane] = acc + b[lane];
}

// ========================= BatchNorm =========================
constexpr int BN_BLOCKS   = 512;
constexpr int BN_ROWS_PER = (N_NODES + BN_BLOCKS - 1) / BN_BLOCKS;  // 98

__global__ __launch_bounds__(256) void bn_stats_ker(const float* __restrict__ A,
                                                    float* __restrict__ stats) {
  const int tid = threadIdx.x;
  const int c   = tid & 127;
  const int rs  = tid >> 7;
  const int r0  = blockIdx.x * BN_ROWS_PER;
  const int re  = min(r0 + BN_ROWS_PER, N_NODES);
  float s = 0.f, sq = 0.f;
  for (int r = r0 + rs; r < re; r += 2) {
    const float v = A[(long)r * 128 + c];
    s += v; sq += v * v;
  }
  atomicAdd(&stats[c], s);
  atomicAdd(&stats[128 + c], sq);
}

__global__ void bn_final_ker(const float* __restrict__ stats,
                             const float* __restrict__ g,
                             const float* __restrict__ be,
                             float* __restrict__ ss) {
  const int c = threadIdx.x;  // 128 threads
  const float mean = stats[c] * (1.0f / N_NODES);
  const float var  = stats[128 + c] * (1.0f / N_NODES) - mean * mean;
  const float sc   = g[c] * rsqrtf(var + BN_EPS);
  ss[c]       = sc;
  ss[128 + c] = be[c] - mean * sc;
}

// ---------------------------------------------------------------------------
extern "C" void kernel_launch(void* const* d_in, const int* in_sizes, int n_in,
                              void* d_out, int out_size, void* d_ws, size_t ws_size,
                              hipStream_t stream) {
  const float* x    = (const float*)d_in[0];
  const int*   erow = (const int*)d_in[1];
  const int*   ecol = (const int*)d_in[2];
  const float* ew   = (const float*)d_in[3];
  const float* W0   = (const float*)d_in[4];
  const float* g0   = (const float*)d_in[6];
  const float* be0  = (const float*)d_in[7];
  const float* W1   = (const float*)d_in[8];
  const float* g1   = (const float*)d_in[10];
  const float* be1  = (const float*)d_in[11];
  const float* W2   = (const float*)d_in[12];
  const float* b2   = (const float*)d_in[13];
  float* out = (float*)d_out;

  // workspace layout (floats/ints); se kept 8B-aligned
  float* h       = (float*)d_ws;                 // N*128
  float* agg     = h + (long)N_NODES * 128;      // N*128
  float* stats0  = agg + (long)N_NODES * 128;    // 256
  float* stats1  = stats0 + 256;                 // 256
  float* ss      = stats1 + 256;                 // 256
  int*   rowptr  = (int*)(ss + 256);             // N+1 (pad to 50002)
  int*   cursor  = rowptr + 50002;               // N (deg -> cursor)
  int*   partial = cursor + N_NODES;             // SCAN_BLK (pad 256)
  int*   bloff   = partial + 256;                // SCAN_BLK (pad 256)
  int2*  se      = (int2*)(bloff + 256);         // E

  const int g_e       = (E_EDGES + 255) / 256;   // 6250
  const int g_gemm128 = (N_NODES + 31) / 32;     // 1563
  const int g_gemm40  = (N_NODES + 95) / 96;     // 521
  const int g_spmm    = (N_NODES * 64) / 256;    // 12500 (exact)

  // ---- zero cursor + both stats up front (independent) ----
  hipMemsetAsync(cursor, 0, (size_t)N_NODES * 4, stream);
  hipMemsetAsync(stats0, 0, 512 * 4, stream);   // stats0 + stats1

  // ---- CSR build ----
  hist_ker<<<g_e, 256, 0, stream>>>(erow, cursor);
  scan1_ker<<<SCAN_BLK, 256, 0, stream>>>(cursor, partial);
  scan2_ker<<<1, 256, 0, stream>>>(partial, bloff);
  scan3_ker<<<SCAN_BLK, 256, 0, stream>>>(cursor, bloff, rowptr);
  scatter_ker<<<g_e, 256, 0, stream>>>(erow, ecol, ew, rowptr, cursor, se);

  // ---- layer 0 ----
  gemm_ker<128, 32, false><<<g_gemm128, 256, 0, stream>>>(x, W0, h, nullptr);
  spmm_csr128_ker<<<g_spmm, 256, 0, stream>>>(rowptr, se, h, agg);
  bn_stats_ker<<<BN_BLOCKS, 256, 0, stream>>>(agg, stats0);
  bn_final_ker<<<1, 128, 0, stream>>>(stats0, g0, be0, ss);

  // ---- layer 1 (BN0+ReLU fused into GEMM input load) ----
  gemm_ker<128, 32, true><<<g_gemm128, 256, 0, stream>>>(agg, W1, h, ss);
  spmm_csr128_ker<<<g_spmm, 256, 0, stream>>>(rowptr, se, h, agg);
  bn_stats_ker<<<BN_BLOCKS, 256, 0, stream>>>(agg, stats1);
  bn_final_ker<<<1, 128, 0, stream>>>(stats1, g1, be1, ss);

  // ---- layer 2 (BN1+ReLU fused into GEMM, bias b2 fused into SpMM) ----
  gemm_ker<40, 96, true><<<g_gemm40, 256, 0, stream>>>(agg, W2, h, ss);
  spmm_csr40_ker<<<g_spmm, 256, 0, stream>>>(rowptr, se, h, b2, out);
}

// Round 4
// 604.469 us; speedup vs baseline: 11.0251x; 1.1866x over previous
//
#include <hip/hip_runtime.h>
#include <hip/hip_fp16.h>

// ---------------------------------------------------------------------------
// GCN: per-call CSR build (hist / 3-phase parallel scan / scatter),
// then 3x (GEMM -> CSR-SpMM). BN affine+ReLU fused into next GEMM's load.
// H (GEMM output, SpMM gather table) stored fp16: halves gather traffic and
// doubles effective L2 coverage. Aggregation stays fp32.
// b0/b1 dropped: constant per-feature shifts cancel in BN mean-subtraction.
// ---------------------------------------------------------------------------

constexpr int   N_NODES  = 50000;
constexpr int   E_EDGES  = 1600000;
constexpr float BN_EPS   = 1e-5f;
constexpr int   SCAN_BLK = (N_NODES + 255) / 256;  // 196

// ========================= CSR build =========================
__global__ __launch_bounds__(256) void hist_ker(const int* __restrict__ rows,
                                                int* __restrict__ deg) {
  const int gid = blockIdx.x * 256 + threadIdx.x;
  if (gid < E_EDGES) atomicAdd(&deg[rows[gid]], 1);
}

__global__ __launch_bounds__(256) void scan1_ker(const int* __restrict__ deg,
                                                 int* __restrict__ partial) {
  const int r = blockIdx.x * 256 + threadIdx.x;
  int v = (r < N_NODES) ? deg[r] : 0;
#pragma unroll
  for (int o = 32; o > 0; o >>= 1) v += __shfl_down(v, o, 64);
  __shared__ int sh[4];
  if ((threadIdx.x & 63) == 0) sh[threadIdx.x >> 6] = v;
  __syncthreads();
  if (threadIdx.x == 0) partial[blockIdx.x] = sh[0] + sh[1] + sh[2] + sh[3];
}

__global__ __launch_bounds__(256) void scan2_ker(const int* __restrict__ partial,
                                                 int* __restrict__ blockoff) {
  const int t = threadIdx.x;
  int v = (t < SCAN_BLK) ? partial[t] : 0;
  __shared__ int sh[256];
  sh[t] = v;
  __syncthreads();
  for (int off = 1; off < 256; off <<= 1) {
    int u = (t >= off) ? sh[t - off] : 0;
    __syncthreads();
    sh[t] += u;
    __syncthreads();
  }
  blockoff[t] = (t == 0) ? 0 : sh[t - 1];
}

__global__ __launch_bounds__(256) void scan3_ker(int* __restrict__ deg,
                                                 const int* __restrict__ blockoff,
                                                 int* __restrict__ rowptr) {
  const int t = threadIdx.x;
  const int r = blockIdx.x * 256 + t;
  const int v = (r < N_NODES) ? deg[r] : 0;
  __shared__ int sh[256];
  sh[t] = v;
  __syncthreads();
  for (int off = 1; off < 256; off <<= 1) {
    int u = (t >= off) ? sh[t - off] : 0;
    __syncthreads();
    sh[t] += u;
    __syncthreads();
  }
  const int base = blockoff[blockIdx.x];
  if (r < N_NODES) {
    rowptr[r] = base + sh[t] - v;
    deg[r] = 0;
  }
  if (r == N_NODES - 1) rowptr[N_NODES] = base + sh[t];
}

__global__ __launch_bounds__(256) void scatter_ker(const int* __restrict__ rows,
                                                   const int* __restrict__ cols,
                                                   const float* __restrict__ ew,
                                                   const int* __restrict__ rowptr,
                                                   int* __restrict__ cursor,
                                                   int2* __restrict__ se) {
  const int gid = blockIdx.x * 256 + threadIdx.x;
  if (gid >= E_EDGES) return;
  const int r   = rows[gid];
  const int pos = rowptr[r] + atomicAdd(&cursor[r], 1);
  int2 v;
  v.x = cols[gid];
  v.y = __float_as_int(ew[gid]);
  se[pos] = v;
}

// ========================= GEMM =========================
// H[N][FOUT](fp16) = act(X)[N][128](fp32) @ W[128][FOUT];  act = BN+ReLU if FUSE.
template <int FOUT, int ROWS, bool FUSE>
__global__ __launch_bounds__(256) void gemm_ker(const float* __restrict__ X,
                                                const float* __restrict__ W,
                                                __half* __restrict__ H,
                                                const float* __restrict__ ss) {
  constexpr int FQ    = FOUT / 4;
  constexpr int RQ    = ROWS / 4;
  constexpr int UNITS = FQ * RQ;
  static_assert(UNITS <= 256, "tile too big");

  __shared__ float Ws[128 * FOUT];
  __shared__ float Xs[ROWS][129];

  const int tid  = threadIdx.x;
  const int row0 = blockIdx.x * ROWS;

  for (int i = tid; i < 128 * FOUT; i += 256) Ws[i] = W[i];

  for (int q = tid; q < ROWS * 32; q += 256) {
    const int r  = q >> 5;
    const int k4 = (q & 31) * 4;
    int gr = row0 + r;
    if (gr >= N_NODES) gr = N_NODES - 1;
    float4 v = *(const float4*)(X + (long)gr * 128 + k4);
    if constexpr (FUSE) {
      const float4 sc = *(const float4*)(ss + k4);
      const float4 sh = *(const float4*)(ss + 128 + k4);
      v.x = fmaxf(v.x * sc.x + sh.x, 0.f);
      v.y = fmaxf(v.y * sc.y + sh.y, 0.f);
      v.z = fmaxf(v.z * sc.z + sh.z, 0.f);
      v.w = fmaxf(v.w * sc.w + sh.w, 0.f);
    }
    Xs[r][k4 + 0] = v.x; Xs[r][k4 + 1] = v.y;
    Xs[r][k4 + 2] = v.z; Xs[r][k4 + 3] = v.w;
  }
  __syncthreads();

  if (tid < UNITS) {
    const int fq = (tid % FQ) * 4;
    const int rg = (tid / FQ) * 4;
    float4 a0 = {0, 0, 0, 0}, a1 = a0, a2 = a0, a3 = a0;
#pragma unroll 8
    for (int k = 0; k < 128; ++k) {
      const float4 wv = *(const float4*)(Ws + k * FOUT + fq);
      const float x0 = Xs[rg + 0][k];
      const float x1 = Xs[rg + 1][k];
      const float x2 = Xs[rg + 2][k];
      const float x3 = Xs[rg + 3][k];
      a0.x += x0 * wv.x; a0.y += x0 * wv.y; a0.z += x0 * wv.z; a0.w += x0 * wv.w;
      a1.x += x1 * wv.x; a1.y += x1 * wv.y; a1.z += x1 * wv.z; a1.w += x1 * wv.w;
      a2.x += x2 * wv.x; a2.y += x2 * wv.y; a2.z += x2 * wv.z; a2.w += x2 * wv.w;
      a3.x += x3 * wv.x; a3.y += x3 * wv.y; a3.z += x3 * wv.z; a3.w += x3 * wv.w;
    }
    const float4 accs[4] = {a0, a1, a2, a3};
#pragma unroll
    for (int i = 0; i < 4; ++i) {
      const int gr = row0 + rg + i;
      if (gr < N_NODES) {
        __half2 p0 = __floats2half2_rn(accs[i].x, accs[i].y);
        __half2 p1 = __floats2half2_rn(accs[i].z, accs[i].w);
        __half2* dst = (__half2*)(H + (long)gr * FOUT + fq);
        dst[0] = p0;
        dst[1] = p1;
      }
    }
  }
}

// ========================= CSR SpMM =========================
// F=128: one wave per row; lane owns 2 contiguous feats (one 4B half2 gather).
__global__ __launch_bounds__(256) void spmm_csr128_ker(const int* __restrict__ rowptr,
                                                       const int2* __restrict__ se,
                                                       const __half* __restrict__ H,
                                                       float* __restrict__ A) {
  const int gid  = blockIdx.x * 256 + threadIdx.x;
  const int lane = threadIdx.x & 63;
  const int wid  = __builtin_amdgcn_readfirstlane(gid >> 6);
  if (wid >= N_NODES) return;
  const int beg = rowptr[wid];
  const int end = rowptr[wid + 1];
  const __half2* __restrict__ Hl = (const __half2*)H + lane;  // row stride 64 half2
  float acc0 = 0.f, acc1 = 0.f;
  int e = beg;
  for (; e + 4 <= end; e += 4) {
    const int2 e0 = se[e + 0], e1 = se[e + 1], e2 = se[e + 2], e3 = se[e + 3];
    const float2 v0 = __half22float2(Hl[(long)e0.x * 64]);
    const float2 v1 = __half22float2(Hl[(long)e1.x * 64]);
    const float2 v2 = __half22float2(Hl[(long)e2.x * 64]);
    const float2 v3 = __half22float2(Hl[(long)e3.x * 64]);
    const float w0 = __int_as_float(e0.y), w1 = __int_as_float(e1.y);
    const float w2 = __int_as_float(e2.y), w3 = __int_as_float(e3.y);
    acc0 += w0 * v0.x; acc1 += w0 * v0.y;
    acc0 += w1 * v1.x; acc1 += w1 * v1.y;
    acc0 += w2 * v2.x; acc1 += w2 * v2.y;
    acc0 += w3 * v3.x; acc1 += w3 * v3.y;
  }
  for (; e < end; ++e) {
    const int2   ed = se[e];
    const float2 v  = __half22float2(Hl[(long)ed.x * 64]);
    const float  w  = __int_as_float(ed.y);
    acc0 += w * v.x; acc1 += w * v.y;
  }
  float2 o; o.x = acc0; o.y = acc1;
  *(float2*)(A + (long)wid * 128 + lane * 2) = o;
}

// F=40 + bias: one wave per row, lanes 0..39 active.
__global__ __launch_bounds__(256) void spmm_csr40_ker(const int* __restrict__ rowptr,
                                                      const int2* __restrict__ se,
                                                      const __half* __restrict__ H,
                                                      const float* __restrict__ b,
                                                      float* __restrict__ out) {
  const int gid  = blockIdx.x * 256 + threadIdx.x;
  const int lane = threadIdx.x & 63;
  const int wid  = __builtin_amdgcn_readfirstlane(gid >> 6);
  if (wid >= N_NODES) return;
  const int beg = rowptr[wid];
  const int end = rowptr[wid + 1];
  const bool act = lane < 40;
  const int  l   = act ? lane : 0;
  float acc = 0.f;
  int e = beg;
  for (; e + 4 <= end; e += 4) {
    const int2 e0 = se[e + 0], e1 = se[e + 1], e2 = se[e + 2], e3 = se[e + 3];
    const float v0 = __half2float(H[(long)e0.x * 40 + l]);
    const float v1 = __half2float(H[(long)e1.x * 40 + l]);
    const float v2 = __half2float(H[(long)e2.x * 40 + l]);
    const float v3 = __half2float(H[(long)e3.x * 40 + l]);
    acc += __int_as_float(e0.y) * v0;
    acc += __int_as_float(e1.y) * v1;
    acc += __int_as_float(e2.y) * v2;
    acc += __int_as_float(e3.y) * v3;
  }
  for (; e < end; ++e) {
    const int2 ed = se[e];
    acc += __int_as_float(ed.y) * __half2float(H[(long)ed.x * 40 + l]);
  }
  if (act) out[(long)wid * 40 + lane] = acc + b[lane];
}

// ========================= BatchNorm =========================
constexpr int BN_BLOCKS   = 512;
constexpr int BN_ROWS_PER = (N_NODES + BN_BLOCKS - 1) / BN_BLOCKS;  // 98

__global__ __launch_bounds__(256) void bn_stats_ker(const float* __restrict__ A,
                                                    float* __restrict__ stats) {
  const int tid = threadIdx.x;
  const int c   = tid & 127;
  const int rs  = tid >> 7;
  const int r0  = blockIdx.x * BN_ROWS_PER;
  const int re  = min(r0 + BN_ROWS_PER, N_NODES);
  float s = 0.f, sq = 0.f;
  for (int r = r0 + rs; r < re; r += 2) {
    const float v = A[(long)r * 128 + c];
    s += v; sq += v * v;
  }
  atomicAdd(&stats[c], s);
  atomicAdd(&stats[128 + c], sq);
}

__global__ void bn_final_ker(const float* __restrict__ stats,
                             const float* __restrict__ g,
                             const float* __restrict__ be,
                             float* __restrict__ ss) {
  const int c = threadIdx.x;  // 128 threads
  const float mean = stats[c] * (1.0f / N_NODES);
  const float var  = stats[128 + c] * (1.0f / N_NODES) - mean * mean;
  const float sc   = g[c] * rsqrtf(var + BN_EPS);
  ss[c]       = sc;
  ss[128 + c] = be[c] - mean * sc;
}

// ---------------------------------------------------------------------------
extern "C" void kernel_launch(void* const* d_in, const int* in_sizes, int n_in,
                              void* d_out, int out_size, void* d_ws, size_t ws_size,
                              hipStream_t stream) {
  const float* x    = (const float*)d_in[0];
  const int*   erow = (const int*)d_in[1];
  const int*   ecol = (const int*)d_in[2];
  const float* ew   = (const float*)d_in[3];
  const float* W0   = (const float*)d_in[4];
  const float* g0   = (const float*)d_in[6];
  const float* be0  = (const float*)d_in[7];
  const float* W1   = (const float*)d_in[8];
  const float* g1   = (const float*)d_in[10];
  const float* be1  = (const float*)d_in[11];
  const float* W2   = (const float*)d_in[12];
  const float* b2   = (const float*)d_in[13];
  float* out = (float*)d_out;

  // workspace layout
  float*  agg     = (float*)d_ws;                 // N*128 fp32
  __half* h       = (__half*)(agg + (long)N_NODES * 128);  // N*128 fp16
  float*  stats0  = (float*)(h + (long)N_NODES * 128);     // 256
  float*  stats1  = stats0 + 256;                 // 256
  float*  ss      = stats1 + 256;                 // 256
  int*    rowptr  = (int*)(ss + 256);             // N+1 (pad to 50002)
  int*    cursor  = rowptr + 50002;               // N (deg -> cursor)
  int*    partial = cursor + N_NODES;             // SCAN_BLK (pad 256)
  int*    bloff   = partial + 256;                // SCAN_BLK (pad 256)
  int2*   se      = (int2*)(bloff + 256);         // E

  const int g_e       = (E_EDGES + 255) / 256;   // 6250
  const int g_gemm128 = (N_NODES + 31) / 32;     // 1563
  const int g_gemm40  = (N_NODES + 95) / 96;     // 521
  const int g_spmm    = (N_NODES * 64) / 256;    // 12500 (exact)

  // ---- zero cursor + both stats up front (independent) ----
  hipMemsetAsync(cursor, 0, (size_t)N_NODES * 4, stream);
  hipMemsetAsync(stats0, 0, 512 * 4, stream);

  // ---- CSR build ----
  hist_ker<<<g_e, 256, 0, stream>>>(erow, cursor);
  scan1_ker<<<SCAN_BLK, 256, 0, stream>>>(cursor, partial);
  scan2_ker<<<1, 256, 0, stream>>>(partial, bloff);
  scan3_ker<<<SCAN_BLK, 256, 0, stream>>>(cursor, bloff, rowptr);
  scatter_ker<<<g_e, 256, 0, stream>>>(erow, ecol, ew, rowptr, cursor, se);

  // ---- layer 0 ----
  gemm_ker<128, 32, false><<<g_gemm128, 256, 0, stream>>>(x, W0, h, nullptr);
  spmm_csr128_ker<<<g_spmm, 256, 0, stream>>>(rowptr, se, h, agg);
  bn_stats_ker<<<BN_BLOCKS, 256, 0, stream>>>(agg, stats0);
  bn_final_ker<<<1, 128, 0, stream>>>(stats0, g0, be0, ss);

  // ---- layer 1 (BN0+ReLU fused into GEMM input load) ----
  gemm_ker<128, 32, true><<<g_gemm128, 256, 0, stream>>>(agg, W1, h, ss);
  spmm_csr128_ker<<<g_spmm, 256, 0, stream>>>(rowptr, se, h, agg);
  bn_stats_ker<<<BN_BLOCKS, 256, 0, stream>>>(agg, stats1);
  bn_final_ker<<<1, 128, 0, stream>>>(stats1, g1, be1, ss);

  // ---- layer 2 (BN1+ReLU fused into GEMM, bias b2 fused into SpMM) ----
  gemm_ker<40, 96, true><<<g_gemm40, 256, 0, stream>>>(agg, W2, h, ss);
  spmm_csr40_ker<<<g_spmm, 256, 0, stream>>>(rowptr, se, h, b2, out);
}

// Round 5
// 600.533 us; speedup vs baseline: 11.0974x; 1.0066x over previous
//
#include <hip/hip_runtime.h>
#include <hip/hip_fp16.h>

// ---------------------------------------------------------------------------
// GCN: per-call CSR build (hist / 3-phase scan / XCD-bucketed scatter),
// then 3x (GEMM -> CSR-SpMM). BN finalize+affine+ReLU fused into next GEMM.
// H (gather table) fp16. b0/b1 dropped (cancel in BN mean-subtraction).
// ---------------------------------------------------------------------------

constexpr int   N_NODES  = 50000;
constexpr int   E_EDGES  = 1600000;
constexpr float BN_EPS   = 1e-5f;
constexpr int   SCAN_BLK = (N_NODES + 255) / 256;  // 196
constexpr int   ROWS_PER_BUCKET = (N_NODES + 7) / 8;  // 6250
constexpr int   SC_BLOCKS = 1024;                  // multiple of 8

// ========================= CSR build =========================
__global__ __launch_bounds__(256) void hist_ker(const int* __restrict__ rows,
                                                int* __restrict__ deg) {
  const int gid = blockIdx.x * 256 + threadIdx.x;
  if (gid < E_EDGES) atomicAdd(&deg[rows[gid]], 1);
}

__global__ __launch_bounds__(256) void scan1_ker(const int* __restrict__ deg,
                                                 int* __restrict__ partial) {
  const int r = blockIdx.x * 256 + threadIdx.x;
  int v = (r < N_NODES) ? deg[r] : 0;
#pragma unroll
  for (int o = 32; o > 0; o >>= 1) v += __shfl_down(v, o, 64);
  __shared__ int sh[4];
  if ((threadIdx.x & 63) == 0) sh[threadIdx.x >> 6] = v;
  __syncthreads();
  if (threadIdx.x == 0) partial[blockIdx.x] = sh[0] + sh[1] + sh[2] + sh[3];
}

__global__ __launch_bounds__(256) void scan2_ker(const int* __restrict__ partial,
                                                 int* __restrict__ blockoff) {
  const int t = threadIdx.x;
  int v = (t < SCAN_BLK) ? partial[t] : 0;
  __shared__ int sh[256];
  sh[t] = v;
  __syncthreads();
  for (int off = 1; off < 256; off <<= 1) {
    int u = (t >= off) ? sh[t - off] : 0;
    __syncthreads();
    sh[t] += u;
    __syncthreads();
  }
  blockoff[t] = (t == 0) ? 0 : sh[t - 1];
}

__global__ __launch_bounds__(256) void scan3_ker(int* __restrict__ deg,
                                                 const int* __restrict__ blockoff,
                                                 int* __restrict__ rowptr) {
  const int t = threadIdx.x;
  const int r = blockIdx.x * 256 + t;
  const int v = (r < N_NODES) ? deg[r] : 0;
  __shared__ int sh[256];
  sh[t] = v;
  __syncthreads();
  for (int off = 1; off < 256; off <<= 1) {
    int u = (t >= off) ? sh[t - off] : 0;
    __syncthreads();
    sh[t] += u;
    __syncthreads();
  }
  const int base = blockoff[blockIdx.x];
  if (r < N_NODES) {
    rowptr[r] = base + sh[t] - v;
    deg[r] = 0;
  }
  if (r == N_NODES - 1) rowptr[N_NODES] = base + sh[t];
}

// XCD-bucketed scatter: blocks with blockIdx%8==p handle rows in bucket p,
// so each bucket's ~1.6MB se region stays resident in one XCD's L2 and the
// 8B writes merge into full lines before writeback.
__global__ __launch_bounds__(256) void scatter_ker(const int* __restrict__ rows,
                                                   const int* __restrict__ cols,
                                                   const float* __restrict__ ew,
                                                   const int* __restrict__ rowptr,
                                                   int* __restrict__ cursor,
                                                   int2* __restrict__ se) {
  const int xcd    = blockIdx.x & 7;
  const int sub    = blockIdx.x >> 3;
  const int nsub   = gridDim.x >> 3;
  const int rlo    = xcd * ROWS_PER_BUCKET;
  const int rhi    = min(rlo + ROWS_PER_BUCKET, N_NODES);
  const int tcount = nsub * 256;
  const int tid    = sub * 256 + threadIdx.x;
  for (int q = tid; q < E_EDGES / 4; q += tcount) {
    const int4 r4 = ((const int4*)rows)[q];
    const int  e0 = q * 4;
#define SC_ONE(RR, EI)                                                        \
    if ((RR) >= rlo && (RR) < rhi) {                                          \
      const int pos = rowptr[RR] + atomicAdd(&cursor[RR], 1);                 \
      int2 v; v.x = cols[EI]; v.y = __float_as_int(ew[EI]);                   \
      se[pos] = v;                                                            \
    }
    SC_ONE(r4.x, e0 + 0)
    SC_ONE(r4.y, e0 + 1)
    SC_ONE(r4.z, e0 + 2)
    SC_ONE(r4.w, e0 + 3)
#undef SC_ONE
  }
}

// ========================= GEMM =========================
// H[N][FOUT](fp16) = act(X)[N][128](fp32) @ W[128][FOUT].
// act (FUSE): BN finalize from raw stats (computed per-block) + affine + ReLU.
template <int FOUT, int ROWS, bool FUSE>
__global__ __launch_bounds__(256) void gemm_ker(const float* __restrict__ X,
                                                const float* __restrict__ W,
                                                __half* __restrict__ H,
                                                const float* __restrict__ stats,
                                                const float* __restrict__ g,
                                                const float* __restrict__ be) {
  constexpr int FQ    = FOUT / 4;
  constexpr int RQ    = ROWS / 4;
  constexpr int UNITS = FQ * RQ;
  static_assert(UNITS <= 256, "tile too big");

  __shared__ float Ws[128 * FOUT];
  __shared__ float Xs[ROWS][129];
  __shared__ float ssc[128], ssh[128];

  const int tid  = threadIdx.x;
  const int row0 = blockIdx.x * ROWS;

  if constexpr (FUSE) {
    if (tid < 128) {
      const float mean = stats[tid] * (1.0f / N_NODES);
      const float var  = stats[128 + tid] * (1.0f / N_NODES) - mean * mean;
      const float sc   = g[tid] * rsqrtf(var + BN_EPS);
      ssc[tid] = sc;
      ssh[tid] = be[tid] - mean * sc;
    }
    __syncthreads();
  }

  for (int i = tid; i < 128 * FOUT; i += 256) Ws[i] = W[i];

  for (int q = tid; q < ROWS * 32; q += 256) {
    const int r  = q >> 5;
    const int k4 = (q & 31) * 4;
    int gr = row0 + r;
    if (gr >= N_NODES) gr = N_NODES - 1;
    float4 v = *(const float4*)(X + (long)gr * 128 + k4);
    if constexpr (FUSE) {
      v.x = fmaxf(v.x * ssc[k4 + 0] + ssh[k4 + 0], 0.f);
      v.y = fmaxf(v.y * ssc[k4 + 1] + ssh[k4 + 1], 0.f);
      v.z = fmaxf(v.z * ssc[k4 + 2] + ssh[k4 + 2], 0.f);
      v.w = fmaxf(v.w * ssc[k4 + 3] + ssh[k4 + 3], 0.f);
    }
    Xs[r][k4 + 0] = v.x; Xs[r][k4 + 1] = v.y;
    Xs[r][k4 + 2] = v.z; Xs[r][k4 + 3] = v.w;
  }
  __syncthreads();

  if (tid < UNITS) {
    const int fq = (tid % FQ) * 4;
    const int rg = (tid / FQ) * 4;
    float4 a0 = {0, 0, 0, 0}, a1 = a0, a2 = a0, a3 = a0;
#pragma unroll 8
    for (int k = 0; k < 128; ++k) {
      const float4 wv = *(const float4*)(Ws + k * FOUT + fq);
      const float x0 = Xs[rg + 0][k];
      const float x1 = Xs[rg + 1][k];
      const float x2 = Xs[rg + 2][k];
      const float x3 = Xs[rg + 3][k];
      a0.x += x0 * wv.x; a0.y += x0 * wv.y; a0.z += x0 * wv.z; a0.w += x0 * wv.w;
      a1.x += x1 * wv.x; a1.y += x1 * wv.y; a1.z += x1 * wv.z; a1.w += x1 * wv.w;
      a2.x += x2 * wv.x; a2.y += x2 * wv.y; a2.z += x2 * wv.z; a2.w += x2 * wv.w;
      a3.x += x3 * wv.x; a3.y += x3 * wv.y; a3.z += x3 * wv.z; a3.w += x3 * wv.w;
    }
    const float4 accs[4] = {a0, a1, a2, a3};
#pragma unroll
    for (int i = 0; i < 4; ++i) {
      const int gr = row0 + rg + i;
      if (gr < N_NODES) {
        __half2 p0 = __floats2half2_rn(accs[i].x, accs[i].y);
        __half2 p1 = __floats2half2_rn(accs[i].z, accs[i].w);
        __half2* dst = (__half2*)(H + (long)gr * FOUT + fq);
        dst[0] = p0;
        dst[1] = p1;
      }
    }
  }
}

// ========================= CSR SpMM =========================
__global__ __launch_bounds__(256) void spmm_csr128_ker(const int* __restrict__ rowptr,
                                                       const int2* __restrict__ se,
                                                       const __half* __restrict__ H,
                                                       float* __restrict__ A) {
  const int gid  = blockIdx.x * 256 + threadIdx.x;
  const int lane = threadIdx.x & 63;
  const int wid  = __builtin_amdgcn_readfirstlane(gid >> 6);
  if (wid >= N_NODES) return;
  const int beg = rowptr[wid];
  const int end = rowptr[wid + 1];
  const __half2* __restrict__ Hl = (const __half2*)H + lane;  // row stride 64
  float acc0 = 0.f, acc1 = 0.f;
  int e = beg;
  for (; e + 4 <= end; e += 4) {
    const int2 e0 = se[e + 0], e1 = se[e + 1], e2 = se[e + 2], e3 = se[e + 3];
    const float2 v0 = __half22float2(Hl[(long)e0.x * 64]);
    const float2 v1 = __half22float2(Hl[(long)e1.x * 64]);
    const float2 v2 = __half22float2(Hl[(long)e2.x * 64]);
    const float2 v3 = __half22float2(Hl[(long)e3.x * 64]);
    const float w0 = __int_as_float(e0.y), w1 = __int_as_float(e1.y);
    const float w2 = __int_as_float(e2.y), w3 = __int_as_float(e3.y);
    acc0 += w0 * v0.x; acc1 += w0 * v0.y;
    acc0 += w1 * v1.x; acc1 += w1 * v1.y;
    acc0 += w2 * v2.x; acc1 += w2 * v2.y;
    acc0 += w3 * v3.x; acc1 += w3 * v3.y;
  }
  for (; e < end; ++e) {
    const int2   ed = se[e];
    const float2 v  = __half22float2(Hl[(long)ed.x * 64]);
    const float  w  = __int_as_float(ed.y);
    acc0 += w * v.x; acc1 += w * v.y;
  }
  float2 o; o.x = acc0; o.y = acc1;
  *(float2*)(A + (long)wid * 128 + lane * 2) = o;
}

__global__ __launch_bounds__(256) void spmm_csr40_ker(const int* __restrict__ rowptr,
                                                      const int2* __restrict__ se,
                                                      const __half* __restrict__ H,
                                                      const float* __restrict__ b,
                                                      float* __restrict__ out) {
  const int gid  = blockIdx.x * 256 + threadIdx.x;
  const int lane = threadIdx.x & 63;
  const int wid  = __builtin_amdgcn_readfirstlane(gid >> 6);
  if (wid >= N_NODES) return;
  const int beg = rowptr[wid];
  const int end = rowptr[wid + 1];
  const bool act = lane < 40;
  const int  l   = act ? lane : 0;
  float acc = 0.f;
  int e = beg;
  for (; e + 4 <= end; e += 4) {
    const int2 e0 = se[e + 0], e1 = se[e + 1], e2 = se[e + 2], e3 = se[e + 3];
    const float v0 = __half2float(H[(long)e0.x * 40 + l]);
    const float v1 = __half2float(H[(long)e1.x * 40 + l]);
    const float v2 = __half2float(H[(long)e2.x * 40 + l]);
    const float v3 = __half2float(H[(long)e3.x * 40 + l]);
    acc += __int_as_float(e0.y) * v0;
    acc += __int_as_float(e1.y) * v1;
    acc += __int_as_float(e2.y) * v2;
    acc += __int_as_float(e3.y) * v3;
  }
  for (; e < end; ++e) {
    const int2 ed = se[e];
    acc += __int_as_float(ed.y) * __half2float(H[(long)ed.x * 40 + l]);
  }
  if (act) out[(long)wid * 40 + lane] = acc + b[lane];
}

// ========================= BatchNorm stats =========================
constexpr int BN_BLOCKS   = 512;
constexpr int BN_ROWS_PER = (N_NODES + BN_BLOCKS - 1) / BN_BLOCKS;  // 98

__global__ __launch_bounds__(256) void bn_stats_ker(const float* __restrict__ A,
                                                    float* __restrict__ stats) {
  const int tid = threadIdx.x;
  const int c   = tid & 127;
  const int rs  = tid >> 7;
  const int r0  = blockIdx.x * BN_ROWS_PER;
  const int re  = min(r0 + BN_ROWS_PER, N_NODES);
  float s = 0.f, sq = 0.f;
  for (int r = r0 + rs; r < re; r += 2) {
    const float v = A[(long)r * 128 + c];
    s += v; sq += v * v;
  }
  atomicAdd(&stats[c], s);
  atomicAdd(&stats[128 + c], sq);
}

// ---------------------------------------------------------------------------
extern "C" void kernel_launch(void* const* d_in, const int* in_sizes, int n_in,
                              void* d_out, int out_size, void* d_ws, size_t ws_size,
                              hipStream_t stream) {
  const float* x    = (const float*)d_in[0];
  const int*   erow = (const int*)d_in[1];
  const int*   ecol = (const int*)d_in[2];
  const float* ew   = (const float*)d_in[3];
  const float* W0   = (const float*)d_in[4];
  const float* g0   = (const float*)d_in[6];
  const float* be0  = (const float*)d_in[7];
  const float* W1   = (const float*)d_in[8];
  const float* g1   = (const float*)d_in[10];
  const float* be1  = (const float*)d_in[11];
  const float* W2   = (const float*)d_in[12];
  const float* b2   = (const float*)d_in[13];
  float* out = (float*)d_out;

  // workspace layout
  float*  agg     = (float*)d_ws;                          // N*128 fp32
  __half* h       = (__half*)(agg + (long)N_NODES * 128);  // N*128 fp16
  float*  stats0  = (float*)(h + (long)N_NODES * 128);     // 256
  float*  stats1  = stats0 + 256;                          // 256
  int*    rowptr  = (int*)(stats1 + 256);                  // N+1 (pad 50002)
  int*    cursor  = rowptr + 50002;                        // N (deg -> cursor)
  int*    partial = cursor + N_NODES;                      // pad 256
  int*    bloff   = partial + 256;                         // pad 256
  int2*   se      = (int2*)(bloff + 256);                  // E

  const int g_e       = (E_EDGES + 255) / 256;   // 6250
  const int g_gemm128 = (N_NODES + 31) / 32;     // 1563
  const int g_gemm40  = (N_NODES + 95) / 96;     // 521
  const int g_spmm    = (N_NODES * 64) / 256;    // 12500

  // ---- zero cursor + both stats up front ----
  hipMemsetAsync(cursor, 0, (size_t)N_NODES * 4, stream);
  hipMemsetAsync(stats0, 0, 512 * 4, stream);

  // ---- CSR build ----
  hist_ker<<<g_e, 256, 0, stream>>>(erow, cursor);
  scan1_ker<<<SCAN_BLK, 256, 0, stream>>>(cursor, partial);
  scan2_ker<<<1, 256, 0, stream>>>(partial, bloff);
  scan3_ker<<<SCAN_BLK, 256, 0, stream>>>(cursor, bloff, rowptr);
  scatter_ker<<<SC_BLOCKS, 256, 0, stream>>>(erow, ecol, ew, rowptr, cursor, se);

  // ---- layer 0 ----
  gemm_ker<128, 32, false><<<g_gemm128, 256, 0, stream>>>(x, W0, h, nullptr, nullptr, nullptr);
  spmm_csr128_ker<<<g_spmm, 256, 0, stream>>>(rowptr, se, h, agg);
  bn_stats_ker<<<BN_BLOCKS, 256, 0, stream>>>(agg, stats0);

  // ---- layer 1 (BN0 finalize+affine+ReLU fused into GEMM input load) ----
  gemm_ker<128, 32, true><<<g_gemm128, 256, 0, stream>>>(agg, W1, h, stats0, g0, be0);
  spmm_csr128_ker<<<g_spmm, 256, 0, stream>>>(rowptr, se, h, agg);
  bn_stats_ker<<<BN_BLOCKS, 256, 0, stream>>>(agg, stats1);

  // ---- layer 2 (BN1 fused into GEMM, bias b2 fused into SpMM) ----
  gemm_ker<40, 96, true><<<g_gemm40, 256, 0, stream>>>(agg, W2, h, stats1, g1, be1);
  spmm_csr40_ker<<<g_spmm, 256, 0, stream>>>(rowptr, se, h, b2, out);
}